// Round 5
// baseline (224.897 us; speedup 1.0000x reference)
//
#include <hip/hip_runtime.h>
#include <stdint.h>

// Conv2DUF: 3x3 s1 p1 conv, x[32][128][56][56] f32, weight[1152][256] f32
// (k = c*9 + kh*3 + kw), bias[256] f32 -> out[32][256][56][56] f32.
// bf16 implicit GEMM: M = 32*56*56 = 100352, N = 256, K = 1152.
//  ws: xt = bf16 x, GROUPED layout [c8grp(16)][B][58][58][8]  (halo = 0)
//      wt = bf16 weight reordered  [9][256][128]              (K-contiguous)
// R7: barrier-free GEMM. Tile = 1 image x 2 output rows (BM=112, grid 896),
//     256 thr / 4 waves (N-split), A footprint (16grp x 4 rows x 58 = 60KB)
//     LDS-resident -> 2 independent blocks/CU (cross-block overlap replaces
//     intra-block pipelining). B (wt, L2-hot) read straight into registers,
//     reg-double-buffered, prefetch distance 1 K-tile. Main loop has ZERO
//     barriers / explicit waitcnt -> no lockstep stall (the wall in R2-R6).

#define C_INQ 128
#define C_OUTQ 256
#define HDIM 56
#define WDIM 56
#define BDIM 32
#define HP 58
#define WP 58
#define HWPIX (HDIM * WDIM)                         // 3136
#define GSTRIDE (BDIM * HP * WP * 8)                // 861184 ushorts per c8-group
#define XT_ELEMS ((size_t)16 * GSTRIDE)             // 13,778,944
#define XT_BYTES (XT_ELEMS * 2)                     // 27,557,888

typedef __bf16 bf16x8 __attribute__((ext_vector_type(8)));
typedef unsigned short ushort8 __attribute__((ext_vector_type(8)));
typedef float floatx4 __attribute__((ext_vector_type(4)));

__device__ __forceinline__ unsigned short f2bf(float f) {
  union { float f; unsigned int u; } v; v.f = f;
  unsigned int u = v.u;
  unsigned int r = u + 0x7FFFu + ((u >> 16) & 1u);   // RNE (finite inputs)
  return (unsigned short)(r >> 16);
}
__device__ __forceinline__ unsigned int pack2(float a, float b) {
  return (unsigned int)f2bf(a) | ((unsigned int)f2bf(b) << 16);
}

// ---------------- kernel 1 (fused prep):
//   blocks [0, 1856):     x NCHW f32 -> xt [g][B][58][58][8] bf16, zero halo
//   blocks [1856, 2000):  weight [1152][256] f32 -> wt [9][256][128] bf16
#define PAD_BLOCKS (BDIM * HP)      // 1856
__global__ __launch_bounds__(256) void prep_kernel(
    const float* __restrict__ x, unsigned short* __restrict__ xt,
    const float* __restrict__ w, unsigned short* __restrict__ wt) {
  const int t = threadIdx.x;
  if (blockIdx.x < PAD_BLOCKS) {
    const int blk = blockIdx.x;
    const int b = blk / HP;
    const int hp = blk - b * HP;
    uint4* __restrict__ xt4 = (uint4*)xt;  // one uint4 = 8 channels of a pixel
    if (hp == 0 || hp == HP - 1) {         // top/bottom halo rows
      for (int i = t; i < 16 * WP; i += 256) {
        int g = i / WP, wp = i - g * WP;
        xt4[((size_t)(g * BDIM + b) * HP + hp) * WP + wp] = make_uint4(0, 0, 0, 0);
      }
      return;
    }
    const int h = hp - 1;
    if (t < 224) {                         // 16 groups x 14 float4 along w
      const int g = t / 14;
      const int w4 = (t - g * 14) * 4;     // 0..52
      const float* xp = x + ((size_t)b * C_INQ + g * 8) * HWPIX + h * WDIM + w4;
      float4 L0 = *(const float4*)(xp);
      float4 L1 = *(const float4*)(xp + HWPIX);
      float4 L2 = *(const float4*)(xp + 2 * HWPIX);
      float4 L3 = *(const float4*)(xp + 3 * HWPIX);
      float4 L4 = *(const float4*)(xp + 4 * HWPIX);
      float4 L5 = *(const float4*)(xp + 5 * HWPIX);
      float4 L6 = *(const float4*)(xp + 6 * HWPIX);
      float4 L7 = *(const float4*)(xp + 7 * HWPIX);
      uint4* dst = xt4 + ((size_t)(g * BDIM + b) * HP + hp) * WP + 1 + w4;
      dst[0] = make_uint4(pack2(L0.x, L1.x), pack2(L2.x, L3.x),
                          pack2(L4.x, L5.x), pack2(L6.x, L7.x));
      dst[1] = make_uint4(pack2(L0.y, L1.y), pack2(L2.y, L3.y),
                          pack2(L4.y, L5.y), pack2(L6.y, L7.y));
      dst[2] = make_uint4(pack2(L0.z, L1.z), pack2(L2.z, L3.z),
                          pack2(L4.z, L5.z), pack2(L6.z, L7.z));
      dst[3] = make_uint4(pack2(L0.w, L1.w), pack2(L2.w, L3.w),
                          pack2(L4.w, L5.w), pack2(L6.w, L7.w));
    } else {                               // 32 spare threads: left/right halo
      const int r = t - 224;
      const int g = r >> 1;
      const int wp = (r & 1) * (WP - 1);
      xt4[((size_t)(g * BDIM + b) * HP + hp) * WP + wp] = make_uint4(0, 0, 0, 0);
    }
  } else {
    const int bx = blockIdx.x - PAD_BLOCKS;  // 0..143
    const int khw = bx >> 4;
    const int r4 = bx & 15;
    const int n0w = (r4 >> 2) * 64;
    const int c32 = (r4 & 3) * 32;
    __shared__ float lds[32 * 66];           // [c][n], stride 66
#pragma unroll
    for (int r = 0; r < 8; ++r) {
      int idx = r * 256 + t;                 // 32*64 = 2048
      int n = idx & 63, c = idx >> 6;
      lds[c * 66 + n] = w[(size_t)((c32 + c) * 9 + khw) * C_OUTQ + n0w + n];
    }
    __syncthreads();
    {
      int n = t >> 2, c8 = (t & 3) * 8;
      const float* s = lds + c8 * 66 + n;
      uint4 o;
      o.x = pack2(s[0],   s[66]);
      o.y = pack2(s[132], s[198]);
      o.z = pack2(s[264], s[330]);
      o.w = pack2(s[396], s[462]);
      *(uint4*)(wt + (size_t)khw * (C_OUTQ * C_INQ) + (size_t)(n0w + n) * C_INQ + c32 + c8) = o;
    }
  }
}

// ---------------- kernel 2: barrier-free implicit GEMM.
// Tile: image b, output rows 2ht..2ht+1, all 56 w (BM=112). BN=256 full.
// 4 waves (pure N-split): wave tile 112m x 64n -> acc[7][4].
// LDS: A footprint only, 16 regions x 240 granules (232 = 4x58 used) = 60KB.
// B: per-wave global->reg fragments, reg-double-buffered, prefetch dist 1 kt.
#define REG2 240                          // granules per A-region (padded)
#define AG2 (16 * REG2)                   // 3840 granules = 61,440 B

__global__ __launch_bounds__(256, 2) void conv_gemm_kernel(
    const unsigned short* __restrict__ xt,
    const unsigned short* __restrict__ wt,
    const float* __restrict__ bias,
    float* __restrict__ out) {
  __shared__ __align__(16) unsigned short ldsA[AG2 * 8];   // 61,440 B

  const int t = threadIdx.x;              // 0..255
  const int lane = t & 63;
  const int wave = t >> 6;                // 0..3
  // bijective XCD swizzle (896 % 8 == 0): XCD k owns 112 consecutive bids
  // = 4 whole images (~3.4MB xt slice + wt 0.6MB ~= its 4MB L2).
  const int bid = ((int)blockIdx.x & 7) * 112 + ((int)blockIdx.x >> 3);
  const int b = bid / 28;                 // image
  const int ht = bid - b * 28;            // row-pair index
  const int hp0 = ht * 2;                 // padded-row base of 4-row footprint

  // ---- prologue: stage entire A footprint (15 uniform rounds)
#pragma unroll
  for (int r = 0; r < 15; ++r) {
    int G = r * 256 + t;                  // 0..3839
    int gi = G / REG2;                    // region (= c8 group) 0..15
    int q = G - gi * REG2;
    if (q >= 4 * 58) q = 0;               // pad lanes reload a valid granule
    const unsigned short* src =
        xt + ((size_t)(gi * BDIM + b) * (HP * WP) + hp0 * WP + q) * 8;
    __builtin_amdgcn_global_load_lds(
        (const __attribute__((address_space(1))) unsigned int*)src,
        (__attribute__((address_space(3))) unsigned int*)(ldsA + G * 8),
        16, 0, 0);
  }

  const int wn = wave * 64;
  const int mrow = lane & 15;
  const int quad = lane >> 4;

  int agb[7];                             // A base granule: quad-region + pixel
#pragma unroll
  for (int i = 0; i < 7; ++i) {
    int m = i * 16 + mrow;                // 0..111
    int lh = m / 56;
    int w = m - lh * 56;
    agb[i] = quad * REG2 + lh * 58 + w;
  }
  const unsigned short* bptr[4];          // per-lane wt base (row + quad slot)
#pragma unroll
  for (int j = 0; j < 4; ++j)
    bptr[j] = wt + (wn + j * 16 + mrow) * C_INQ + quad * 8;

  float bv[4];
#pragma unroll
  for (int j = 0; j < 4; ++j) bv[j] = bias[wn + j * 16 + mrow];

  floatx4 acc[7][4] = {};

#define BC8(p) __builtin_bit_cast(bf16x8, *(const ushort8*)(p))

  bf16x8 bA[4][2], bB[4][2];              // reg double-buffer for B frags
  // loadB(kt): 8 global_load_dwordx4 from wt (L1/L2-hot), no LDS, no swizzle
#define LOADB(dst, KT)                                                    \
  {                                                                       \
    const int khw_ = (KT) >> 1, ch_ = (KT) & 1;                           \
    const int off_ = khw_ * (C_OUTQ * C_INQ) + ch_ * 64;                  \
    _Pragma("unroll")                                                     \
    for (int j = 0; j < 4; ++j) {                                         \
      dst[j][0] = BC8(bptr[j] + off_);                                    \
      dst[j][1] = BC8(bptr[j] + off_ + 32);                               \
    }                                                                     \
  }

  // compute(kt): 14 ds_read_b128 (A) + 112 MFMA, no sync (A is read-only)
#define COMPUTE(bf, KT)                                                   \
  {                                                                       \
    const int khw_ = (KT) >> 1, ch_ = (KT) & 1;                           \
    const int kh_ = khw_ / 3, kw_ = khw_ - kh_ * 3;                       \
    const int kadd_ = ch_ * (8 * REG2) + kh_ * 58 + kw_;                  \
    __builtin_amdgcn_s_setprio(1);                                        \
    _Pragma("unroll")                                                     \
    for (int i = 0; i < 7; ++i) {                                         \
      bf16x8 a0 = BC8(ldsA + (agb[i] + kadd_) * 8);                       \
      bf16x8 a1 = BC8(ldsA + (agb[i] + kadd_ + 4 * REG2) * 8);            \
      _Pragma("unroll")                                                   \
      for (int j = 0; j < 4; ++j)                                         \
        acc[i][j] = __builtin_amdgcn_mfma_f32_16x16x32_bf16(              \
            a0, bf[j][0], acc[i][j], 0, 0, 0);                            \
      _Pragma("unroll")                                                   \
      for (int j = 0; j < 4; ++j)                                         \
        acc[i][j] = __builtin_amdgcn_mfma_f32_16x16x32_bf16(              \
            a1, bf[j][1], acc[i][j], 0, 0, 0);                            \
    }                                                                     \
    __builtin_amdgcn_s_setprio(0);                                        \
  }

  LOADB(bA, 0);
  __syncthreads();                        // the ONLY barrier: A now resident

#pragma unroll 1
  for (int khw = 0; khw < 9; ++khw) {     // kt = khw*2 + {0,1}
    const int kt = khw * 2;
    LOADB(bB, kt + 1);                    // prefetch odd (hidden under 112 MFMA)
    COMPUTE(bA, kt);
    if (khw < 8) LOADB(bA, kt + 2);       // prefetch next even
    COMPUTE(bB, kt + 1);
  }
#undef LOADB
#undef COMPUTE
#undef BC8

  // epilogue: C/D layout col(n) = lane&15, row(m) = quad*4 + reg.
  // 4 consecutive pixels per lane -> one float4 store.
  float* ob = out + (size_t)b * (C_OUTQ * HWPIX) + ht * 112;
#pragma unroll
  for (int i = 0; i < 7; ++i) {
    const int mloc = i * 16 + quad * 4;
#pragma unroll
    for (int j = 0; j < 4; ++j) {
      const int n = wn + j * 16 + mrow;
      floatx4 v = acc[i][j];
      v[0] += bv[j]; v[1] += bv[j]; v[2] += bv[j]; v[3] += bv[j];
      *(floatx4*)(ob + (size_t)n * HWPIX + mloc) = v;
    }
  }
}

extern "C" void kernel_launch(void* const* d_in, const int* in_sizes, int n_in,
                              void* d_out, int out_size, void* d_ws, size_t ws_size,
                              hipStream_t stream) {
  const float* x    = (const float*)d_in[0];
  const float* w    = (const float*)d_in[1];
  const float* bias = (const float*)d_in[2];
  float* out = (float*)d_out;

  unsigned short* xt = (unsigned short*)d_ws;
  unsigned short* wt = (unsigned short*)((char*)d_ws + XT_BYTES);  // +589,824 B

  hipLaunchKernelGGL(prep_kernel, dim3(PAD_BLOCKS + 144), dim3(256), 0, stream,
                     x, xt, w, wt);
  hipLaunchKernelGGL(conv_gemm_kernel, dim3(896), dim3(256), 0, stream,
                     xt, wt, bias, out);
}